// Round 9
// baseline (2147.418 us; speedup 1.0000x reference)
//
#include <hip/hip_runtime.h>
#include <math.h>

// ---------------- compile-time problem constants ----------------
#define TOTE 5400000   // total edges
#define TOTN 234000    // total node rows (all types concatenated)
#define TOTC 514000    // total dst slots over 14 edge types
#define HID  128

// bucketed CSR build (two-pass stable binning, no global atomics)
#define NBUK 499        // coarse dst-range buckets over all 14 edge types (span <= 2048 slots)
#define NBLK 1024       // blocks in hist_k / scatter_k (NBLK == 256*4 for scan_blk_k)

// ws carve (~224.4 MB, proven-safe ceiling 245.8 MB)
// d_out scratch: col (21.6MB), overwritten by the head GEMM at the end.

typedef __attribute__((ext_vector_type(8))) short short8;
typedef __attribute__((ext_vector_type(8))) __bf16 bf16x8;
typedef __attribute__((ext_vector_type(4))) float floatx4;
typedef __attribute__((ext_vector_type(2))) float float2v;

__constant__ int c_EPRE[15]   = {0,1000000,2000000,2500000,3000000,3200000,3400000,3600000,3800000,3900000,4000000,4300000,4600000,5000000,5400000};
__constant__ int c_ECNT[14]   = {1000000,1000000,500000,500000,200000,200000,200000,200000,100000,100000,300000,300000,400000,400000};
__constant__ int c_CNTOFF[14] = {0,40000,140000,143000,183000,203000,243000,263000,303000,311000,351000,411000,451000,454000};
__constant__ int c_CNTN[14]   = {40000,100000,3000,40000,20000,40000,20000,40000,8000,40000,60000,40000,3000,60000};
__constant__ int c_SRCOFF[14] = {0,100000,100000,140000,100000,143000,100000,143000,100000,163000,100000,171000,171000,231000};
__constant__ int c_NODEPRE[8] = {0,100000,140000,143000,163000,171000,231000,234000};
// bucket tables: per-type dst shift and bucket-id base (prefix of ceil(CNTN/2^sh))
__constant__ int c_BSH[14]   = {9,10,6,10,10,11,10,11,10,11,11,11,6,11};
__constant__ int c_BBASE[15] = {0,79,177,224,264,284,304,324,344,352,372,402,422,469,499};

static __device__ __forceinline__ unsigned short f2bf(float f) {
    unsigned u = __float_as_uint(f);
    u = u + 0x7FFFu + ((u >> 16) & 1u);
    return (unsigned short)(u >> 16);
}
static __device__ __forceinline__ float bf2f(unsigned short s) {
    return __uint_as_float(((unsigned)s) << 16);
}

struct EdgeArgs { const int* ei[14]; };

// ---------------- CSR build: stable two-pass binning ----------------
// Record: (slot_local:11 | src_global:18), < 2^29.

__global__ __launch_bounds__(256) void hist_k(EdgeArgs a, int* __restrict__ blkHist) {
    __shared__ int h[NBUK];
    int t = threadIdx.x;
    for (int i = t; i < NBUK; i += 256) h[i] = 0;
    __syncthreads();
    const int per = (TOTE + NBLK - 1) / NBLK;
    int s = blockIdx.x * per;
    int eEnd = min(s + per, TOTE);
    for (int g = s + t; g < eEnd; g += 256) {
        int e = 0;
        while (g >= c_EPRE[e + 1]) e++;
        int k = g - c_EPRE[e];
        int dst = a.ei[e][c_ECNT[e] + k];
        atomicAdd(&h[c_BBASE[e] + (dst >> c_BSH[e])], 1);
    }
    __syncthreads();
    for (int i = t; i < NBUK; i += 256) blkHist[(size_t)i * NBLK + blockIdx.x] = h[i];
}

__global__ __launch_bounds__(256) void scan_blk_k(int* __restrict__ blkHist, int* __restrict__ bktCnt) {
    int b = blockIdx.x;
    int* p = blkHist + (size_t)b * NBLK;
    int t = threadIdx.x;
    int4 v = *(int4*)&p[t * 4];
    int s = v.x + v.y + v.z + v.w;
    int lane = t & 63, w = t >> 6;
    __shared__ int wt[4];
    int incl = s;
    #pragma unroll
    for (int d = 1; d < 64; d <<= 1) { int o = __shfl_up(incl, d); if (lane >= d) incl += o; }
    if (lane == 63) wt[w] = incl;
    __syncthreads();
    int wb = 0;
    for (int i = 0; i < w; i++) wb += wt[i];
    int excl = incl - s + wb;
    int4 o;
    o.x = excl; o.y = excl + v.x; o.z = excl + v.x + v.y; o.w = excl + v.x + v.y + v.z;
    *(int4*)&p[t * 4] = o;
    if (t == 255) bktCnt[b] = excl + s;
}

__global__ __launch_bounds__(512) void scans2_k(const int* __restrict__ bktCnt, int* __restrict__ bktEdgeBase) {
    int t = threadIdx.x;
    int v = (t < NBUK) ? bktCnt[t] : 0;
    int lane = t & 63, w = t >> 6;
    __shared__ int wt[8];
    int incl = v;
    #pragma unroll
    for (int d = 1; d < 64; d <<= 1) { int o = __shfl_up(incl, d); if (lane >= d) incl += o; }
    if (lane == 63) wt[w] = incl;
    __syncthreads();
    int wb = 0;
    for (int i = 0; i < w; i++) wb += wt[i];
    int excl = incl - v + wb;
    if (t < NBUK) bktEdgeBase[t] = excl;
    if (t == NBUK - 1) bktEdgeBase[NBUK] = excl + v;
}

__global__ __launch_bounds__(256) void scatter_k(EdgeArgs a, const int* __restrict__ blkHist,
        const int* __restrict__ bktEdgeBase, unsigned* __restrict__ pool) {
    __shared__ int cur[NBUK];
    int t = threadIdx.x;
    for (int i = t; i < NBUK; i += 256)
        cur[i] = bktEdgeBase[i] + blkHist[(size_t)i * NBLK + blockIdx.x];
    __syncthreads();
    const int per = (TOTE + NBLK - 1) / NBLK;
    int s = blockIdx.x * per;
    int eEnd = min(s + per, TOTE);
    for (int g = s + t; g < eEnd; g += 256) {
        int e = 0;
        while (g >= c_EPRE[e + 1]) e++;
        int k = g - c_EPRE[e];
        int src = a.ei[e][k];
        int dst = a.ei[e][c_ECNT[e] + k];
        int sh = c_BSH[e];
        unsigned rec = ((unsigned)(dst & ((1 << sh) - 1)) << 18) | (unsigned)(c_SRCOFF[e] + src);
        int p = atomicAdd(&cur[c_BBASE[e] + (dst >> sh)], 1);
        pool[p] = rec;
    }
}

__global__ __launch_bounds__(256) void csrfill_k(
        const unsigned* __restrict__ pool, const int* __restrict__ bktEdgeBase,
        int* __restrict__ cnt, int* __restrict__ cursor, float* __restrict__ invdeg,
        int* __restrict__ col) {
    __shared__ int hist[2048];
    __shared__ int cur[2048];
    __shared__ int wtot[4];
    __shared__ int wbase[4];
    int b = blockIdx.x;
    int t = threadIdx.x;
    int e = 0;
    while (b >= c_BBASE[e + 1]) e++;
    int lb = b - c_BBASE[e];
    int sh = c_BSH[e];
    int s0t = lb << sh;
    int span = min(1 << sh, c_CNTN[e] - s0t);
    int gs0 = c_CNTOFF[e] + s0t;
    int ebase = bktEdgeBase[b];
    int nrec = bktEdgeBase[b + 1] - ebase;

    for (int i = t; i < span; i += 256) hist[i] = 0;
    __syncthreads();
    for (int i = t; i < nrec; i += 256) atomicAdd(&hist[pool[ebase + i] >> 18], 1);
    __syncthreads();
    int base = t * 8, loc = 0, lv[8];
    #pragma unroll
    for (int i = 0; i < 8; i++) {
        int ii = base + i;
        int v = (ii < span) ? hist[ii] : 0;
        lv[i] = loc; loc += v;
    }
    int lane = t & 63, w = t >> 6;
    int incl = loc;
    #pragma unroll
    for (int d = 1; d < 64; d <<= 1) { int o = __shfl_up(incl, d); if (lane >= d) incl += o; }
    if (lane == 63) wtot[w] = incl;
    __syncthreads();
    if (t == 0) { int s2 = 0; for (int i = 0; i < 4; i++) { wbase[i] = s2; s2 += wtot[i]; } }
    __syncthreads();
    int texcl = incl - loc + wbase[w];
    #pragma unroll
    for (int i = 0; i < 8; i++) {
        int ii = base + i;
        if (ii < span) cur[ii] = texcl + lv[i];
    }
    __syncthreads();
    for (int i = t; i < span; i += 256) {
        int c = hist[i];
        cnt[gs0 + i] = c;
        cursor[gs0 + i] = ebase + cur[i] + c;     // end semantics
        invdeg[gs0 + i] = 1.0f / fmaxf((float)c, 1.0f);
    }
    __syncthreads();
    for (int i = t; i < nrec; i += 256) {
        unsigned rec = pool[ebase + i];
        int p = atomicAdd(&cur[rec >> 18], 1);
        col[ebase + p] = (int)(rec & 0x3FFFFu);
    }
}

// ---------------- conversions ----------------
struct XArgs { const float* x[7]; };
__global__ __launch_bounds__(256) void convx_k(XArgs a, unsigned short* __restrict__ hbf) {
    int i4 = blockIdx.x * 256 + threadIdx.x;
    if (i4 >= TOTN * 32) return;           // float4 index
    int idx = i4 * 4;
    int t = 0;
    while (idx >= c_NODEPRE[t + 1] * 128) t++;
    float4 v = *(const float4*)&a.x[t][idx - c_NODEPRE[t] * 128];
    uint2 p;
    p.x = (unsigned)f2bf(v.x) | ((unsigned)f2bf(v.y) << 16);
    p.y = (unsigned)f2bf(v.z) | ((unsigned)f2bf(v.w) << 16);
    *(uint2*)&hbf[idx] = p;
}

// weight slots: 0-6 Wp, 7-48 Wl(l*14+e), 49-90 Wr, 91 Wu, 92 Wv  (93 * 16384 elements)
struct WArgs { const float* Wp; const float* Wl; const float* Wr; const float* Wu; const float* Wv; };
__global__ __launch_bounds__(256) void convw_k(WArgs a, unsigned short* __restrict__ wbf) {
    int i4 = blockIdx.x * 256 + threadIdx.x;
    if (i4 >= 93 * 4096) return;
    int idx = i4 * 4;
    int m = idx >> 14;
    int i = idx & 16383;
    const float* src;
    if (m < 7)       src = a.Wp + (size_t)m * 16384;
    else if (m < 49) src = a.Wl + (size_t)(m - 7) * 16384;
    else if (m < 91) src = a.Wr + (size_t)(m - 49) * 16384;
    else if (m == 91) src = a.Wu;
    else              src = a.Wv;
    float4 v = *(const float4*)&src[i];
    uint2 p;
    p.x = (unsigned)f2bf(v.x) | ((unsigned)f2bf(v.y) << 16);
    p.y = (unsigned)f2bf(v.z) | ((unsigned)f2bf(v.w) << 16);
    *(uint2*)&wbf[idx] = p;
}

// ---------------- aggregation: quarter-wave, 16 slots/quarter, batched col loads ----------------
// Each 16-lane quarter owns 16 CONSECUTIVE slots (sum-of-16 smooths degree imbalance
// ~4x vs one-slot-per-quarter). Neighbor indices loaded coalesced in batches of 16
// (lane li loads cp[j+li], one 64B quarter-coalesced load) and broadcast via __shfl
// from the quarter's own lanes (16x fewer col-load issues). Row loads unrolled x8:
// 8 rows in flight per quarter before first accumulate.
#define ACC8v(u) do { \
    v01 += (float2v){__uint_as_float((u).x << 16), __uint_as_float((u).x & 0xFFFF0000u)}; \
    v23 += (float2v){__uint_as_float((u).y << 16), __uint_as_float((u).y & 0xFFFF0000u)}; \
    v45 += (float2v){__uint_as_float((u).z << 16), __uint_as_float((u).z & 0xFFFF0000u)}; \
    v67 += (float2v){__uint_as_float((u).w << 16), __uint_as_float((u).w & 0xFFFF0000u)}; } while (0)

__global__ __launch_bounds__(256) void agg_k(
        const int* __restrict__ cnt, const int* __restrict__ cursor,
        const float* __restrict__ inv_deg, const int* __restrict__ col,
        const unsigned short* __restrict__ hbf, unsigned short* __restrict__ slotb) {
    int lane = threadIdx.x & 63;
    int li = lane & 15;
    int qb = lane & 48;                               // quarter base lane in wave
    int q = blockIdx.x * 16 + (threadIdx.x >> 4);     // global quarter id
    int s0 = q * 16;
    int sEnd = min(s0 + 16, TOTC);
    for (int row = s0; row < sEnd; row++) {
        int nn = cnt[row];
        int rs = cursor[row] - nn;       // cursor==end
        const int* cp = col + rs;
        float2v v01 = {0.f, 0.f}, v23 = {0.f, 0.f}, v45 = {0.f, 0.f}, v67 = {0.f, 0.f};
        int j = 0;
        while (j < nn) {
            int take = min(nn - j, 16);
            int cidx = (li < take) ? cp[j + li] : 0;  // coalesced 64B per quarter
            int r = 0;
            for (; r + 8 <= take; r += 8) {
                int c0 = __shfl(cidx, qb + r)     << 7;
                int c1 = __shfl(cidx, qb + r + 1) << 7;
                int c2 = __shfl(cidx, qb + r + 2) << 7;
                int c3 = __shfl(cidx, qb + r + 3) << 7;
                int c4 = __shfl(cidx, qb + r + 4) << 7;
                int c5 = __shfl(cidx, qb + r + 5) << 7;
                int c6 = __shfl(cidx, qb + r + 6) << 7;
                int c7 = __shfl(cidx, qb + r + 7) << 7;
                uint4 u0 = *(const uint4*)&hbf[c0 + li * 8];
                uint4 u1 = *(const uint4*)&hbf[c1 + li * 8];
                uint4 u2 = *(const uint4*)&hbf[c2 + li * 8];
                uint4 u3 = *(const uint4*)&hbf[c3 + li * 8];
                uint4 u4 = *(const uint4*)&hbf[c4 + li * 8];
                uint4 u5 = *(const uint4*)&hbf[c5 + li * 8];
                uint4 u6 = *(const uint4*)&hbf[c6 + li * 8];
                uint4 u7 = *(const uint4*)&hbf[c7 + li * 8];
                ACC8v(u0); ACC8v(u1); ACC8v(u2); ACC8v(u3);
                ACC8v(u4); ACC8v(u5); ACC8v(u6); ACC8v(u7);
            }
            for (; r < take; r++) {
                int c = __shfl(cidx, qb + r) << 7;
                uint4 u = *(const uint4*)&hbf[c + li * 8];
                ACC8v(u);
            }
            j += take;
        }
        float inv = inv_deg[row];
        float v[8] = {v01.x, v01.y, v23.x, v23.y, v45.x, v45.y, v67.x, v67.y};
        uint4 o;
        o.x = (unsigned)f2bf(v[0] * inv) | ((unsigned)f2bf(v[1] * inv) << 16);
        o.y = (unsigned)f2bf(v[2] * inv) | ((unsigned)f2bf(v[3] * inv) << 16);
        o.z = (unsigned)f2bf(v[4] * inv) | ((unsigned)f2bf(v[5] * inv) << 16);
        o.w = (unsigned)f2bf(v[6] * inv) | ((unsigned)f2bf(v[7] * inv) << 16);
        *(uint4*)&slotb[(size_t)row * HID + li * 8] = o;
    }
}

// ---------------- fused per-node-type layer: GEMMs + l2norm-sum + LN + relu ----------------
struct FusArgs {
    int blockPrefix[8];
    int ns[7];
    int a1off[7][6];                   // slot-range base per feeding edge type
    const unsigned short* W1[7][6];    // Wl
    const unsigned short* W2[7][6];    // Wr
    const float* bias[7][6];
    int nodepre[7];
    int nrows[7];
    float invnd[7];
};

__global__ __launch_bounds__(256) void fusedln_k(FusArgs g,
        unsigned short* __restrict__ hbf, const unsigned short* __restrict__ slotb,
        const float* __restrict__ ln_g, const float* __restrict__ ln_b, int l) {
    __shared__ short As2[64 * 168];    // persistent h tile: row*168 + chunk*40 + elem
    __shared__ short A1c[64 * 40];     // per-k-chunk A1 tile
    __shared__ short W1c[128 * 40];
    __shared__ short W2c[128 * 40];
    int b = blockIdx.x;
    int t = 0;
    while (b >= g.blockPrefix[t + 1]) t++;
    int nrows = g.nrows[t];
    int row0 = (b - g.blockPrefix[t]) * 64;
    int dst0 = g.nodepre[t] + row0;
    int tid = threadIdx.x;
    int w = tid >> 6, lane = tid & 63;
    int q = lane >> 4, m15 = lane & 15;

    // stage the 64 h rows (zero-fill tail)
    {
        const uint4* h4 = (const uint4*)hbf;
        #pragma unroll
        for (int it = 0; it < 4; it++) {
            int c = tid + it * 256;            // 0..1023: row(6b) x kc16(4b)
            int row = c >> 4, kc = c & 15;
            uint4 v = make_uint4(0u, 0u, 0u, 0u);
            if (row0 + row < nrows) v = h4[(size_t)(dst0 + row) * 16 + kc];
            *(uint4*)&As2[row * 168 + (kc >> 2) * 40 + (kc & 3) * 8] = v;
        }
    }

    floatx4 accsum[8];
    #pragma unroll
    for (int bb = 0; bb < 8; bb++) accsum[bb] = (floatx4){0.f, 0.f, 0.f, 0.f};

    int ns = g.ns[t];
    for (int ei = 0; ei < ns; ei++) {
        const uint4* A14 = (const uint4*)(slotb + (size_t)g.a1off[t][ei] * HID);
        const uint4* W14 = (const uint4*)g.W1[t][ei];
        const uint4* W24 = (const uint4*)g.W2[t][ei];
        floatx4 acc[8];
        #pragma unroll
        for (int bb = 0; bb < 8; bb++) acc[bb] = (floatx4){0.f, 0.f, 0.f, 0.f};
        for (int k0 = 0; k0 < 4; k0++) {
            __syncthreads();
            {   // A1 chunk: 64 rows x 32 k
                int row = tid >> 2, kc = tid & 3;
                uint4 v = make_uint4(0u, 0u, 0u, 0u);
                if (row0 + row < nrows) v = A14[(size_t)(row0 + row) * 16 + k0 * 4 + kc];
                *(uint4*)&A1c[row * 40 + kc * 8] = v;
            }
            #pragma unroll
            for (int i = 0; i < 2; i++) {   // W chunks: 128 cols x 32 k each
                int idx = tid + i * 256;
                int c = idx >> 2, kc = idx & 3;
                *(uint4*)&W1c[c * 40 + kc * 8] = W14[(size_t)c * 16 + k0 * 4 + kc];
                *(uint4*)&W2c[c * 40 + kc * 8] = W24[(size_t)c * 16 + k0 * 4 + kc];
            }
            __syncthreads();
            bf16x8 a1 = __builtin_bit_cast(bf16x8, *(const short8*)&A1c[(w * 16 + m15) * 40 + q * 8]);
            bf16x8 a2 = __builtin_bit_cast(bf16x8, *(const short8*)&As2[(w * 16 + m15) * 168 + k0 * 40 + q * 8]);
            #pragma unroll
            for (int bb = 0; bb < 8; bb++) {
                bf16x8 w1 = __builtin_bit_cast(bf16x8, *(const short8*)&W1c[(bb * 16 + m15) * 40 + q * 8]);
                bf16x8 w2 = __builtin_bit_cast(bf16x8, *(const short8*)&W2c[(bb * 16 + m15) * 40 + q * 8]);
                acc[bb] = __builtin_amdgcn_mfma_f32_16x16x32_bf16(a1, w1, acc[bb], 0, 0, 0);
                acc[bb] = __builtin_amdgcn_mfma_f32_16x16x32_bf16(a2, w2, acc[bb], 0, 0, 0);
            }
        }
        // edge-type epilogue: bias + per-row l2norm, accumulate
        const float* bias = g.bias[t][ei];
        #pragma unroll
        for (int bb = 0; bb < 8; bb++) {
            float bv = bias[bb * 16 + m15];
            #pragma unroll
            for (int reg = 0; reg < 4; reg++) acc[bb][reg] += bv;
        }
        #pragma unroll
        for (int reg = 0; reg < 4; reg++) {
            float ss = 0.f;
            #pragma unroll
            for (int bb = 0; bb < 8; bb++) ss += acc[bb][reg] * acc[bb][reg];
            ss += __shfl_xor(ss, 1);
            ss += __shfl_xor(ss, 2);
            ss += __shfl_xor(ss, 4);
            ss += __shfl_xor(ss, 8);
            float sc = 1.0f / fmaxf(sqrtf(ss), 1e-12f);
            #pragma unroll
            for (int bb = 0; bb < 8; bb++) accsum[bb][reg] += acc[bb][reg] * sc;
        }
    }

    // final: x = accsum*invnd + residual; LayerNorm; relu; write h
    float invnd = g.invnd[t];
    const float* gg = ln_g + ((size_t)l * 7 + t) * HID;
    const float* bbp = ln_b + ((size_t)l * 7 + t) * HID;
    float gv[8], bv2[8];
    #pragma unroll
    for (int bb = 0; bb < 8; bb++) {
        gv[bb]  = gg[bb * 16 + m15];
        bv2[bb] = bbp[bb * 16 + m15];
    }
    #pragma unroll
    for (int reg = 0; reg < 4; reg++) {
        int lrow = w * 16 + q * 4 + reg;          // C-layout row
        float x[8];
        #pragma unroll
        for (int bb = 0; bb < 8; bb++) {
            float resid = bf2f((unsigned short)As2[lrow * 168 + (bb >> 1) * 40 + (bb & 1) * 16 + m15]);
            x[bb] = accsum[bb][reg] * invnd + resid;
        }
        float s = 0.f;
        #pragma unroll
        for (int bb = 0; bb < 8; bb++) s += x[bb];
        s += __shfl_xor(s, 1);
        s += __shfl_xor(s, 2);
        s += __shfl_xor(s, 4);
        s += __shfl_xor(s, 8);
        float mean = s * (1.0f / 128.0f);
        float vs = 0.f;
        #pragma unroll
        for (int bb = 0; bb < 8; bb++) { float d = x[bb] - mean; vs += d * d; }
        vs += __shfl_xor(vs, 1);
        vs += __shfl_xor(vs, 2);
        vs += __shfl_xor(vs, 4);
        vs += __shfl_xor(vs, 8);
        float rstd = rsqrtf(vs * (1.0f / 128.0f) + 1e-5f);
        if (row0 + lrow < nrows) {
            unsigned short* o = hbf + (size_t)(dst0 + lrow) * HID;
            #pragma unroll
            for (int bb = 0; bb < 8; bb++) {
                float y = (x[bb] - mean) * rstd * gv[bb] + bv2[bb];
                o[bb * 16 + m15] = f2bf(fmaxf(y, 0.f));
            }
        }
    }
}

// ---------------- MFMA GEMM (input projection / heads) ----------------
struct GemmArgs {
    int blockPrefix[15];
    const unsigned short* A1[14];
    const unsigned short* W1[14];
    const float* bias[14]; void* out[14];
    int rows[14];
};

template<int MODE>
__global__ __launch_bounds__(256) void gemm_k(GemmArgs g) {
    __shared__ short As[64 * 40];
    __shared__ short Ws[128 * 40];
    int b = blockIdx.x;
    int s = 0;
    while (b >= g.blockPrefix[s + 1]) s++;
    int rows = g.rows[s];
    int row0 = (b - g.blockPrefix[s]) * 64;
    int t = threadIdx.x;
    int w = t >> 6, lane = t & 63;
    int q = lane >> 4, m15 = lane & 15;

    floatx4 acc[8];
    #pragma unroll
    for (int bb = 0; bb < 8; bb++) acc[bb] = (floatx4){0.f, 0.f, 0.f, 0.f};

    const uint4* A4 = (const uint4*)g.A1[s];
    const uint4* W4 = (const uint4*)g.W1[s];
    for (int k0 = 0; k0 < 128; k0 += 32) {
        __syncthreads();
        {   // A tile
            int row = t >> 2, kc = t & 3;
            uint4 v = make_uint4(0u, 0u, 0u, 0u);
            if (row0 + row < rows) v = A4[(size_t)(row0 + row) * 16 + (k0 >> 3) + kc];
            *(uint4*)&As[row * 40 + kc * 8] = v;
        }
        #pragma unroll
        for (int i = 0; i < 2; i++) {   // W tile
            int idx = t + i * 256;
            int c = idx >> 2, kc = idx & 3;
            uint4 v = W4[(size_t)c * 16 + (k0 >> 3) + kc];
            *(uint4*)&Ws[c * 40 + kc * 8] = v;
        }
        __syncthreads();
        bf16x8 af = __builtin_bit_cast(bf16x8, *(const short8*)&As[(w * 16 + m15) * 40 + q * 8]);
        #pragma unroll
        for (int bb = 0; bb < 8; bb++) {
            bf16x8 bf = __builtin_bit_cast(bf16x8, *(const short8*)&Ws[(bb * 16 + m15) * 40 + q * 8]);
            acc[bb] = __builtin_amdgcn_mfma_f32_16x16x32_bf16(af, bf, acc[bb], 0, 0, 0);
        }
    }

    const float* bias = g.bias[s];
    #pragma unroll
    for (int bb = 0; bb < 8; bb++) {
        float bv = bias[bb * 16 + m15];
        #pragma unroll
        for (int reg = 0; reg < 4; reg++) acc[bb][reg] += bv;
    }
    if (MODE != 0) {
        #pragma unroll
        for (int reg = 0; reg < 4; reg++) {
            float ss = 0.f;
            #pragma unroll
            for (int bb = 0; bb < 8; bb++) ss += acc[bb][reg] * acc[bb][reg];
            ss += __shfl_xor(ss, 1);
            ss += __shfl_xor(ss, 2);
            ss += __shfl_xor(ss, 4);
            ss += __shfl_xor(ss, 8);
            float sc = 1.0f / fmaxf(sqrtf(ss), 1e-12f);
            #pragma unroll
            for (int bb = 0; bb < 8; bb++) acc[bb][reg] *= sc;
        }
    }
    int rbase = row0 + w * 16 + q * 4;
    if (MODE == 3) {
        float* out = (float*)g.out[s];
        #pragma unroll
        for (int reg = 0; reg < 4; reg++) {
            int r = rbase + reg;
            if (r < rows) {
                float* o = out + (size_t)r * HID;
                #pragma unroll
                for (int bb = 0; bb < 8; bb++) o[bb * 16 + m15] = acc[bb][reg];
            }
        }
    } else {
        unsigned short* out = (unsigned short*)g.out[s];
        #pragma unroll
        for (int reg = 0; reg < 4; reg++) {
            int r = rbase + reg;
            if (r < rows) {
                unsigned short* o = out + (size_t)r * HID;
                #pragma unroll
                for (int bb = 0; bb < 8; bb++) o[bb * 16 + m15] = f2bf(acc[bb][reg]);
            }
        }
    }
}

// ---------------- host ----------------
extern "C" void kernel_launch(void* const* d_in, const int* in_sizes, int n_in,
                              void* d_out, int out_size, void* d_ws, size_t ws_size,
                              hipStream_t stream) {
    (void)in_sizes; (void)n_in; (void)out_size; (void)ws_size;
    const float* Wp   = (const float*)d_in[21];
    const float* bp   = (const float*)d_in[22];
    const float* bl   = (const float*)d_in[24];
    const float* ln_g = (const float*)d_in[26];
    const float* ln_b = (const float*)d_in[27];
    const float* bu   = (const float*)d_in[29];
    const float* bv   = (const float*)d_in[31];
    float* out = (float*)d_out;

    // d_ws carve (~224.4 MB)
    unsigned short* h_bf   = (unsigned short*)d_ws;                  // TOTN*128 bf16
    unsigned short* w_bf   = h_bf + (size_t)TOTN * HID;              // 93*16384 bf16
    unsigned short* slotb  = w_bf + (size_t)93 * 16384;              // TOTC*128 bf16
    int*            cnt    = (int*)(slotb + (size_t)TOTC * HID);     // TOTC
    int*            cursor = cnt + TOTC;                             // TOTC
    float*          invdeg = (float*)(cursor + TOTC);                // TOTC
    unsigned*       pool   = (unsigned*)(invdeg + TOTC);             // TOTE records
    int*            blkHist = (int*)(pool + (size_t)TOTE);           // NBUK*NBLK
    int*            ctrl    = blkHist + (size_t)NBUK * NBLK;         // control block
    int* bktCnt       = ctrl;                 // NBUK
    int* bktEdgeBase  = ctrl + NBUK;          // NBUK+1

    // d_out scratch (overwritten by final head GEMM)
    int* col = (int*)d_out;                                          // TOTE ints

    static const int CNTOFF[14] = {0,40000,140000,143000,183000,203000,243000,263000,303000,311000,351000,411000,451000,454000};
    static const int NODEPRE[8] = {0,100000,140000,143000,163000,171000,231000,234000};
    static const int NT[7]      = {100000,40000,3000,20000,8000,60000,3000};
    static const int FEED_NS[7] = {1,6,1,2,1,2,1};
    static const int FEED_E[7][6] = {
        {1,0,0,0,0,0},
        {0,3,5,7,9,11},
        {2,0,0,0,0,0},
        {4,6,0,0,0,0},
        {8,0,0,0,0,0},
        {10,13,0,0,0,0},
        {12,0,0,0,0,0}};
    static const float INVND[7] = {1.0f, 1.0f/6.0f, 1.0f, 0.5f, 1.0f, 0.5f, 1.0f};

    EdgeArgs ea;
    for (int e = 0; e < 14; e++) ea.ei[e] = (const int*)d_in[7 + e];

    // CSR build: histogram -> scans -> scatter -> per-bucket fill
    hist_k<<<NBLK, 256, 0, stream>>>(ea, blkHist);
    scan_blk_k<<<NBUK, 256, 0, stream>>>(blkHist, bktCnt);
    scans2_k<<<1, 512, 0, stream>>>(bktCnt, bktEdgeBase);
    scatter_k<<<NBLK, 256, 0, stream>>>(ea, blkHist, bktEdgeBase, pool);
    csrfill_k<<<NBUK, 256, 0, stream>>>(pool, bktEdgeBase, cnt, cursor, invdeg, col);

    {   // conversions
        XArgs xa;
        for (int t = 0; t < 7; t++) xa.x[t] = (const float*)d_in[t];
        convx_k<<<(TOTN * 32 + 255) / 256, 256, 0, stream>>>(xa, h_bf);
        WArgs wa = {Wp, (const float*)d_in[23], (const float*)d_in[25],
                    (const float*)d_in[28], (const float*)d_in[30]};
        convw_k<<<(93 * 4096 + 255) / 256, 256, 0, stream>>>(wa, w_bf);
    }

    // input projection (in-place bf16): h_bf[t] = x_bf[t] @ Wp[t]^T + bp[t]
    {
        GemmArgs ga;
        int pre = 0; ga.blockPrefix[0] = 0;
        for (int t = 0; t < 7; t++) {
            ga.A1[t] = h_bf + (size_t)NODEPRE[t] * HID;
            ga.W1[t] = w_bf + (size_t)t * 16384;
            ga.bias[t] = bp + (size_t)t * HID;
            ga.out[t] = h_bf + (size_t)NODEPRE[t] * HID;
            ga.rows[t] = NT[t];
            pre += (NT[t] + 63) / 64;
            ga.blockPrefix[t + 1] = pre;
        }
        for (int s = 7; s < 14; s++) { ga.blockPrefix[s + 1] = pre; ga.rows[s] = 0; }
        gemm_k<0><<<pre, 256, 0, stream>>>(ga);
    }

    // layers: agg + fused(GEMMs+LN) per layer
    FusArgs fa;
    int fgrid;
    {
        int pre = 0; fa.blockPrefix[0] = 0;
        for (int t = 0; t < 7; t++) {
            fa.ns[t] = FEED_NS[t];
            fa.nodepre[t] = NODEPRE[t];
            fa.nrows[t] = NT[t];
            fa.invnd[t] = INVND[t];
            for (int j = 0; j < 6; j++) fa.a1off[t][j] = CNTOFF[FEED_E[t][j]];
            pre += (NT[t] + 63) / 64;
            fa.blockPrefix[t + 1] = pre;
        }
        fgrid = pre;
    }
    for (int l = 0; l < 3; l++) {
        agg_k<<<(TOTC + 255) / 256, 256, 0, stream>>>(cnt, cursor, invdeg, col, h_bf, slotb);
        for (int t = 0; t < 7; t++) {
            for (int j = 0; j < 6; j++) {
                int e = FEED_E[t][j];
                fa.W1[t][j]   = w_bf + (size_t)(7  + l * 14 + e) * 16384;
                fa.W2[t][j]   = w_bf + (size_t)(49 + l * 14 + e) * 16384;
                fa.bias[t][j] = bl + ((size_t)l * 14 + e) * HID;
            }
        }
        fusedln_k<<<fgrid, 256, 0, stream>>>(fa, h_bf, slotb, ln_g, ln_b, l);
    }

    // heads: l2norm(h @ W^T + b) -> fp32 out (overwrites the col scratch in d_out)
    {
        GemmArgs ga;
        ga.blockPrefix[0] = 0;
        ga.A1[0] = h_bf;
        ga.W1[0] = w_bf + (size_t)91 * 16384;
        ga.bias[0] = bu;                        ga.out[0] = out;
        ga.rows[0] = 100000;
        ga.blockPrefix[1] = (100000 + 63) / 64;
        ga.A1[1] = h_bf + (size_t)100000 * HID;
        ga.W1[1] = w_bf + (size_t)92 * 16384;
        ga.bias[1] = bv;                        ga.out[1] = out + (size_t)100000 * HID;
        ga.rows[1] = 40000;
        int tot = ga.blockPrefix[1] + (40000 + 63) / 64;
        for (int s = 2; s < 14; s++) { ga.blockPrefix[s + 1] = tot; ga.rows[s] = 0; }
        ga.blockPrefix[2] = tot;
        gemm_k<3><<<tot, 256, 0, stream>>>(ga);
    }
}